// Round 2
// baseline (82.241 us; speedup 1.0000x reference)
//
#include <hip/hip_runtime.h>
#include <hip/hip_cooperative_groups.h>
#include <math.h>

namespace cg = cooperative_groups;

#define BB 2
#define NN 512
#define DD 128
#define ROWS (BB*NN)     // 1024
#define NR 4             // rows per block
#define NBLK (ROWS/NR)   // 256 blocks = 1 per CU
#define NTHR 512

__device__ __forceinline__ float sigmoidf_(float z){ return 1.0f/(1.0f + __expf(-z)); }

// One cooperative kernel, three phases, one grid sync.
//  Phase 1 (per block, 4 rows): h = xW_lin^T+b ; dotL/dotR = h.W_att ; hm1 = hW_m1'^T+b (global)
//  grid.sync()  -- every block needs its batch's full hm1 + dotR
//  Phase 2: att = sigmoid(dotL[n]+dotR[m]+adj*wA+bA); aggm = sum_m att*relu(hm1[m]+adj*wa1);
//           s_att = sum_m att; adj passthrough copy. All block-local outputs (LDS).
//  Phase 3: 3 GEMVs (W_m2 folded past the sum), residual (h still in register), LN, relu.
__global__ __launch_bounds__(NTHR) void fused(
    const float* __restrict__ x, const float* __restrict__ adj,
    const float* __restrict__ W_lin, const float* __restrict__ b_lin,
    const float* __restrict__ W_m1, const float* __restrict__ b_m1,
    const float* __restrict__ W_m2, const float* __restrict__ b_m2,
    const float* __restrict__ W_att, const float* __restrict__ b_att,
    const float* __restrict__ W_o1, const float* __restrict__ b_o1,
    const float* __restrict__ W_o2, const float* __restrict__ b_o2,
    const float* __restrict__ ln_g, const float* __restrict__ ln_b,
    float* __restrict__ out, float* __restrict__ out_adj,
    float* __restrict__ hm1g, float* __restrict__ dotRg)
{
    const int r0  = blockIdx.x * NR;     // global row base (b*512 + n0)
    const int b   = r0 >> 9;             // batch
    const int t   = threadIdx.x;         // 0..511
    const int rr  = t >> 7;              // row-in-block 0..3 (phases 1,3)
    const int o   = t & 127;             // output dim     (phases 1,3)
    const int wid = (t >> 6) & 1;        // wave within row group

    __shared__ float  hs[NR][DD];        // h (phase1 -> hm1 input)
    __shared__ float  xs[NR][DD];        // x staging / GEMV ping
    __shared__ float  ag2[NR][DD];       // aggm / GEMV pong
    __shared__ float2 aa[NR][NN];        // (adj, att) per row
    __shared__ float2 red[8][NR][64];    // phase-2 partials
    __shared__ float2 wa1s[64];          // W_m1[:,128] d-pairs
    __shared__ float  redsc[2][2][NR];   // 2-wave scalar reductions
    __shared__ float  dl[NR];            // dotL for own rows
    __shared__ float  satt[NR];          // sum_m att

    // ---------------- phase 1 ----------------
    xs[rr][o] = x[(r0 + rr) * DD + o];
    __syncthreads();

    float hreg = b_lin[o];
    {
        const float* wrow = W_lin + o * DD;
        #pragma unroll
        for (int d = 0; d < DD; d += 4) {
            float4 w4 = *(const float4*)(wrow + d);
            float4 a4 = *(const float4*)(&xs[rr][d]);
            hreg = fmaf(a4.x, w4.x, hreg);
            hreg = fmaf(a4.y, w4.y, hreg);
            hreg = fmaf(a4.z, w4.z, hreg);
            hreg = fmaf(a4.w, w4.w, hreg);
        }
    }
    hs[rr][o] = hreg;

    // attention dot products (reduce over o within each 128-thread row group)
    {
        float pl = hreg * W_att[o];
        float pr = hreg * W_att[DD + o];
        #pragma unroll
        for (int off = 32; off >= 1; off >>= 1) {
            pl += __shfl_down(pl, off, 64);
            pr += __shfl_down(pr, off, 64);
        }
        if ((t & 63) == 0) { redsc[wid][0][rr] = pl; redsc[wid][1][rr] = pr; }
    }
    __syncthreads();
    if (t < NR) {
        dl[t]         = redsc[0][0][t] + redsc[1][0][t];
        dotRg[r0 + t] = redsc[0][1][t] + redsc[1][1][t];
    }

    // hm1 = h @ W_m1[:, :128]^T + b_m1  (W_m1 row stride 129)
    {
        float a2 = b_m1[o];
        const float* w2 = W_m1 + o * (DD + 1);
        #pragma unroll
        for (int d = 0; d < DD; d += 4) {
            float4 a4 = *(const float4*)(&hs[rr][d]);
            a2 = fmaf(a4.x, w2[d],     a2);
            a2 = fmaf(a4.y, w2[d + 1], a2);
            a2 = fmaf(a4.z, w2[d + 2], a2);
            a2 = fmaf(a4.w, w2[d + 3], a2);
        }
        hm1g[(r0 + rr) * DD + o] = a2;
    }

    cg::this_grid().sync();

    // ---------------- phase 2 ----------------
    const int g = t >> 6, lane = t & 63;
    if (t < 64)
        wa1s[t] = make_float2(W_m1[(2 * t) * (DD + 1) + DD],
                              W_m1[(2 * t + 1) * (DD + 1) + DD]);
    const float wAdj = W_att[2 * DD];
    const float bA   = b_att[0];
    {
        float drm = dotRg[b * NN + t];
        #pragma unroll
        for (int i = 0; i < NR; i++) {
            float a = adj[(r0 + i) * NN + t];
            out_adj[(r0 + i) * NN + t] = a;
            float z = dl[i] + drm + a * wAdj + bA;
            aa[i][t] = make_float2(a, sigmoidf_(z));
        }
    }
    __syncthreads();

    // s_att: waves 0..3 reduce rows 0..3
    if (g < NR) {
        float s = 0.f;
        #pragma unroll
        for (int k = 0; k < 8; k++) s += aa[g][lane + 64 * k].y;
        #pragma unroll
        for (int off = 32; off >= 1; off >>= 1) s += __shfl_down(s, off, 64);
        if (lane == 0) satt[g] = s;
    }

    // main neighbor sweep: 8 wave-groups split m, thread owns d-pair 2*lane
    {
        float2 agg[NR];
        #pragma unroll
        for (int r = 0; r < NR; r++) agg[r] = make_float2(0.f, 0.f);
        float2 wa = wa1s[lane];
        const float* hbase = hm1g + (size_t)b * NN * DD + 2 * lane;
        #pragma unroll 4
        for (int m = g; m < NN; m += 8) {
            float2 hv = *(const float2*)(hbase + m * DD);
            #pragma unroll
            for (int r = 0; r < NR; r++) {
                float2 at = aa[r][m];                  // LDS broadcast
                float u0 = fmaxf(fmaf(at.x, wa.x, hv.x), 0.f);
                float u1 = fmaxf(fmaf(at.x, wa.y, hv.y), 0.f);
                agg[r].x = fmaf(at.y, u0, agg[r].x);
                agg[r].y = fmaf(at.y, u1, agg[r].y);
            }
        }
        #pragma unroll
        for (int r = 0; r < NR; r++) red[g][r][lane] = agg[r];
    }
    __syncthreads();
    {
        float s = 0.f;
        #pragma unroll
        for (int gg = 0; gg < 8; gg++)
            s += ((const float*)&red[gg][rr][0])[o];
        ag2[rr][o] = s;
    }
    __syncthreads();

    // ---------------- phase 3 ----------------
    float v;
    {   // v1 = aggm @ W_m2^T + b_m2 * s_att
        v = b_m2[o] * satt[rr];
        const float* wrow = W_m2 + o * DD;
        #pragma unroll
        for (int d = 0; d < DD; d += 4) {
            float4 w4 = *(const float4*)(wrow + d);
            float4 a4 = *(const float4*)(&ag2[rr][d]);
            v = fmaf(a4.x, w4.x, v);
            v = fmaf(a4.y, w4.y, v);
            v = fmaf(a4.z, w4.z, v);
            v = fmaf(a4.w, w4.w, v);
        }
    }
    xs[rr][o] = v;
    __syncthreads();

    {   // v2 = relu(v1 @ W_o1^T + b_o1)
        v = b_o1[o];
        const float* wrow = W_o1 + o * DD;
        #pragma unroll
        for (int d = 0; d < DD; d += 4) {
            float4 w4 = *(const float4*)(wrow + d);
            float4 a4 = *(const float4*)(&xs[rr][d]);
            v = fmaf(a4.x, w4.x, v);
            v = fmaf(a4.y, w4.y, v);
            v = fmaf(a4.z, w4.z, v);
            v = fmaf(a4.w, w4.w, v);
        }
        v = fmaxf(v, 0.f);
    }
    ag2[rr][o] = v;     // safe: all ag2 reads completed before previous sync
    __syncthreads();

    {   // v3 = v2 @ W_o2^T + b_o2, + residual h (still in hreg)
        v = b_o2[o];
        const float* wrow = W_o2 + o * DD;
        #pragma unroll
        for (int d = 0; d < DD; d += 4) {
            float4 w4 = *(const float4*)(wrow + d);
            float4 a4 = *(const float4*)(&ag2[rr][d]);
            v = fmaf(a4.x, w4.x, v);
            v = fmaf(a4.y, w4.y, v);
            v = fmaf(a4.z, w4.z, v);
            v = fmaf(a4.w, w4.w, v);
        }
        v += hreg;
    }

    // layernorm over d (128 threads = 2 waves per row)
    {
        float p1 = v, p2 = v * v;
        #pragma unroll
        for (int off = 32; off >= 1; off >>= 1) {
            p1 += __shfl_down(p1, off, 64);
            p2 += __shfl_down(p2, off, 64);
        }
        if ((t & 63) == 0) { redsc[wid][0][rr] = p1; redsc[wid][1][rr] = p2; }
    }
    __syncthreads();
    {
        float sum = redsc[0][0][rr] + redsc[1][0][rr];
        float sq  = redsc[0][1][rr] + redsc[1][1][rr];
        float mu  = sum * (1.0f / DD);
        float var = sq * (1.0f / DD) - mu * mu;
        float inv = rsqrtf(var + 1e-5f);
        out[(r0 + rr) * DD + o] = fmaxf(fmaf((v - mu) * inv, ln_g[o], ln_b[o]), 0.f);
    }
}

extern "C" void kernel_launch(void* const* d_in, const int* in_sizes, int n_in,
                              void* d_out, int out_size, void* d_ws, size_t ws_size,
                              hipStream_t stream)
{
    (void)in_sizes; (void)n_in; (void)out_size; (void)ws_size;
    const float* x     = (const float*)d_in[0];
    const float* adj   = (const float*)d_in[1];
    const float* W_lin = (const float*)d_in[2];
    const float* b_lin = (const float*)d_in[3];
    const float* W_m1  = (const float*)d_in[4];
    const float* b_m1  = (const float*)d_in[5];
    const float* W_m2  = (const float*)d_in[6];
    const float* b_m2  = (const float*)d_in[7];
    const float* W_att = (const float*)d_in[8];
    const float* b_att = (const float*)d_in[9];
    const float* W_o1  = (const float*)d_in[10];
    const float* b_o1  = (const float*)d_in[11];
    const float* W_o2  = (const float*)d_in[12];
    const float* b_o2  = (const float*)d_in[13];
    const float* ln_g  = (const float*)d_in[14];
    const float* ln_b  = (const float*)d_in[15];

    float* out     = (float*)d_out;
    float* out_adj = out + ROWS * DD;          // second output: adj passthrough

    float* ws    = (float*)d_ws;
    float* hm1g  = ws;                          // 1024*128 floats
    float* dotRg = ws + ROWS * DD;              // 1024 floats

    void* args[] = {
        (void*)&x, (void*)&adj,
        (void*)&W_lin, (void*)&b_lin,
        (void*)&W_m1, (void*)&b_m1,
        (void*)&W_m2, (void*)&b_m2,
        (void*)&W_att, (void*)&b_att,
        (void*)&W_o1, (void*)&b_o1,
        (void*)&W_o2, (void*)&b_o2,
        (void*)&ln_g, (void*)&ln_b,
        (void*)&out, (void*)&out_adj,
        (void*)&hm1g, (void*)&dotRg
    };
    hipLaunchCooperativeKernel((const void*)fused, dim3(NBLK), dim3(NTHR),
                               args, 0, stream);
}

// Round 3
// 29.176 us; speedup vs baseline: 2.8187x; 2.8187x over previous
//
#include <hip/hip_runtime.h>
#include <math.h>

#define NN 512
#define DD 128
#define ROWS 1024
#define NR 4

__device__ __forceinline__ float sigmoidf_(float z){ return 1.0f/(1.0f + __expf(-z)); }

// ---------------------------------------------------------------------------
// Kernel 1: per-row transforms (proven R1 structure) + weight transposes.
//   h    = x @ W_lin^T + b_lin
//   hm1  = h @ W_m1[:, :128]^T + b_m1
//   dotL = h . W_att[0:128], dotR = h . W_att[128:256]
//   blocks 0..47 additionally transpose an 8-row slice of W_m2/W_o1/W_o2
//   into Wt (layout [d][o]) for kernel 2's coalesced GEMVs.
// grid 256 x 128 threads; block owns NR=4 rows; thread = output o.
// ---------------------------------------------------------------------------
__global__ __launch_bounds__(128) void k_rows(
    const float* __restrict__ x, const float* __restrict__ W_lin, const float* __restrict__ b_lin,
    const float* __restrict__ W_m1, const float* __restrict__ b_m1,
    const float* __restrict__ W_att,
    const float* __restrict__ W_m2, const float* __restrict__ W_o1, const float* __restrict__ W_o2,
    float* __restrict__ h, float* __restrict__ hm1,
    float* __restrict__ dotL, float* __restrict__ dotR,
    float* __restrict__ Wt_m2, float* __restrict__ Wt_o1, float* __restrict__ Wt_o2)
{
    const int r0 = blockIdx.x * NR;
    const int t  = threadIdx.x;          // output index o
    __shared__ float xs[NR][DD];
    __shared__ float hs[NR][DD];
    __shared__ float red[2][2][NR];      // [wave][L/R][row]

    #pragma unroll
    for (int r = 0; r < NR; r++) xs[r][t] = x[(r0 + r) * DD + t];
    __syncthreads();

    float acc[NR];
    {
        float bl = b_lin[t];
        #pragma unroll
        for (int r = 0; r < NR; r++) acc[r] = bl;
        const float* wrow = W_lin + t * DD;
        for (int d = 0; d < DD; d += 4) {
            float4 w4 = *(const float4*)(wrow + d);
            #pragma unroll
            for (int r = 0; r < NR; r++) {
                float4 a4 = *(const float4*)(&xs[r][d]);
                acc[r] = fmaf(a4.x, w4.x, acc[r]);
                acc[r] = fmaf(a4.y, w4.y, acc[r]);
                acc[r] = fmaf(a4.z, w4.z, acc[r]);
                acc[r] = fmaf(a4.w, w4.w, acc[r]);
            }
        }
    }
    #pragma unroll
    for (int r = 0; r < NR; r++) { h[(r0 + r) * DD + t] = acc[r]; hs[r][t] = acc[r]; }

    // attention dot products (reduce over o = threads)
    {
        float wl = W_att[t], wr = W_att[DD + t];
        float pl[NR], pr[NR];
        #pragma unroll
        for (int r = 0; r < NR; r++) { pl[r] = acc[r] * wl; pr[r] = acc[r] * wr; }
        #pragma unroll
        for (int off = 32; off >= 1; off >>= 1) {
            #pragma unroll
            for (int r = 0; r < NR; r++) {
                pl[r] += __shfl_down(pl[r], off, 64);
                pr[r] += __shfl_down(pr[r], off, 64);
            }
        }
        int wid = t >> 6, lane = t & 63;
        if (lane == 0) {
            #pragma unroll
            for (int r = 0; r < NR; r++) { red[wid][0][r] = pl[r]; red[wid][1][r] = pr[r]; }
        }
    }
    __syncthreads();
    if (t < NR) {
        dotL[r0 + t] = red[0][0][t] + red[1][0][t];
        dotR[r0 + t] = red[0][1][t] + red[1][1][t];
    }

    // hm1 = h @ W_m1[:, :128]^T + b_m1   (W_m1 rows have stride 129)
    {
        float acc2[NR];
        float bm = b_m1[t];
        #pragma unroll
        for (int r = 0; r < NR; r++) acc2[r] = bm;
        const float* wrow = W_m1 + t * (DD + 1);
        for (int d = 0; d < DD; d += 4) {
            float w0 = wrow[d], w1 = wrow[d+1], w2 = wrow[d+2], w3 = wrow[d+3];
            #pragma unroll
            for (int r = 0; r < NR; r++) {
                float4 a4 = *(const float4*)(&hs[r][d]);
                acc2[r] = fmaf(a4.x, w0, acc2[r]);
                acc2[r] = fmaf(a4.y, w1, acc2[r]);
                acc2[r] = fmaf(a4.z, w2, acc2[r]);
                acc2[r] = fmaf(a4.w, w3, acc2[r]);
            }
        }
        #pragma unroll
        for (int r = 0; r < NR; r++) hm1[(r0 + r) * DD + t] = acc2[r];
    }

    // ---- transpose duty: blocks 0..47, one 8-row slice each ----
    if (blockIdx.x < 48) {
        __shared__ float tlds[8][DD];
        const int w = blockIdx.x >> 4;       // which weight
        const int s = blockIdx.x & 15;       // which 8-row slice
        const float* src = (w == 0) ? W_m2 : (w == 1) ? W_o1 : W_o2;
        float*       dst = (w == 0) ? Wt_m2 : (w == 1) ? Wt_o1 : Wt_o2;
        #pragma unroll
        for (int j = 0; j < 8; j++) tlds[j][t] = src[(s * 8 + j) * DD + t];
        __syncthreads();
        float4 v0 = make_float4(tlds[0][t], tlds[1][t], tlds[2][t], tlds[3][t]);
        float4 v1 = make_float4(tlds[4][t], tlds[5][t], tlds[6][t], tlds[7][t]);
        *(float4*)(dst + t * DD + s * 8)     = v0;   // Wt[d=t][o=s*8..+7]
        *(float4*)(dst + t * DD + s * 8 + 4) = v1;
    }
}

// ---------------------------------------------------------------------------
// Kernel 2: fused attention + message aggregation + output network + LN.
// grid 256 x 512 threads; block owns NR=4 rows.
//   Phase A: att = sigmoid(dotL[n]+dotR[m]+adj*wA+bA); s_att; adj passthrough
//   Phase B: aggm[n,d] = sum_m att * relu(hm1[m,d] + adj*wa1[d])
//   Phase C: v1 = aggm@W_m2^T + b_m2*s_att ; v2 = relu(v1@W_o1^T+b_o1);
//            v3 = v2@W_o2^T + b_o2 ; out = relu(LN(h+v3))
//   GEMVs read TRANSPOSED weights: thread (oq=t&31, dg=t>>5) accumulates
//   4 outputs x 4 rows over an 8-wide d-strip -> coalesced 16-line loads.
// ---------------------------------------------------------------------------
__global__ __launch_bounds__(512) void k_msgout(
    const float* __restrict__ adj, const float* __restrict__ hm1,
    const float* __restrict__ dotL, const float* __restrict__ dotR,
    const float* __restrict__ W_m1, const float* __restrict__ W_att, const float* __restrict__ b_att,
    const float* __restrict__ Wt_m2, const float* __restrict__ b_m2,
    const float* __restrict__ Wt_o1, const float* __restrict__ b_o1,
    const float* __restrict__ Wt_o2, const float* __restrict__ b_o2,
    const float* __restrict__ h, const float* __restrict__ ln_g, const float* __restrict__ ln_b,
    float* __restrict__ out, float* __restrict__ out_adj)
{
    const int r0   = blockIdx.x * NR;
    const int b    = r0 >> 9;
    const int t    = threadIdx.x;        // 0..511
    const int g    = t >> 6;             // wave 0..7
    const int lane = t & 63;
    const int rr   = t >> 7;             // row-in-block (combine/LN phases)
    const int o    = t & 127;            // output dim   (combine/LN phases)
    const int oq   = t & 31;             // GEMV: output quad (o = 4*oq..+3)
    const int dg   = t >> 5;             // GEMV: d-group (d = dg*8..+7)

    __shared__ float2 aa[NR][NN];        // (adj, att) 16KB
    __shared__ float2 red[8][NR][64];    // sweep partials 16KB
    __shared__ float  pb[4][4][16][32];  // GEMV partials [j][r][dg][oq] 32KB
    __shared__ float  vs[NR][DD];        // GEMV ping
    __shared__ float  vs2[NR][DD];       // GEMV pong
    __shared__ float2 wa1s[64];
    __shared__ float  satt[NR];
    __shared__ float  redsc[2][2][NR];

    if (t < 64)
        wa1s[t] = make_float2(W_m1[(2 * t) * (DD + 1) + DD],
                              W_m1[(2 * t + 1) * (DD + 1) + DD]);
    const float wAdj = W_att[2 * DD];
    const float bA   = b_att[0];

    // ---- Phase A: attention ----
    {
        float drm = dotR[b * NN + t];
        #pragma unroll
        for (int i = 0; i < NR; i++) {
            float a = adj[(r0 + i) * NN + t];
            out_adj[(r0 + i) * NN + t] = a;
            float z = dotL[r0 + i] + drm + a * wAdj + bA;
            aa[i][t] = make_float2(a, sigmoidf_(z));
        }
    }
    __syncthreads();

    if (g < NR) {   // s_att
        float s = 0.f;
        #pragma unroll
        for (int k = 0; k < 8; k++) s += aa[g][lane + 64 * k].y;
        #pragma unroll
        for (int off = 32; off >= 1; off >>= 1) s += __shfl_down(s, off, 64);
        if (lane == 0) satt[g] = s;
    }

    // ---- Phase B: neighbor sweep ----
    {
        float2 agg[NR];
        #pragma unroll
        for (int r = 0; r < NR; r++) agg[r] = make_float2(0.f, 0.f);
        float2 wa = wa1s[lane];
        const float* hbase = hm1 + (size_t)b * NN * DD + 2 * lane;
        #pragma unroll 4
        for (int m = g; m < NN; m += 8) {
            float2 hv = *(const float2*)(hbase + m * DD);
            #pragma unroll
            for (int r = 0; r < NR; r++) {
                float2 at = aa[r][m];
                float u0 = fmaxf(fmaf(at.x, wa.x, hv.x), 0.f);
                float u1 = fmaxf(fmaf(at.x, wa.y, hv.y), 0.f);
                agg[r].x = fmaf(at.y, u0, agg[r].x);
                agg[r].y = fmaf(at.y, u1, agg[r].y);
            }
        }
        #pragma unroll
        for (int r = 0; r < NR; r++) red[g][r][lane] = agg[r];
    }
    __syncthreads();
    {   // combine sweep partials -> vs = aggm
        float s = 0.f;
        #pragma unroll
        for (int gg = 0; gg < 8; gg++)
            s += ((const float*)&red[gg][rr][0])[o];
        vs[rr][o] = s;
    }
    __syncthreads();

    // ---- Phase C: three GEMVs with transposed weights ----
    // GEMV1: v1 = aggm @ W_m2^T + b_m2 * s_att
    {
        float a0[4], a1[4], a2[4], a3[4];
        #pragma unroll
        for (int r = 0; r < 4; r++) { a0[r]=0.f; a1[r]=0.f; a2[r]=0.f; a3[r]=0.f; }
        #pragma unroll
        for (int k = 0; k < 8; k++) {
            int d = dg * 8 + k;
            float4 w4 = *(const float4*)(Wt_m2 + d * DD + oq * 4);
            #pragma unroll
            for (int r = 0; r < 4; r++) {
                float xv = vs[r][d];
                a0[r] = fmaf(w4.x, xv, a0[r]);
                a1[r] = fmaf(w4.y, xv, a1[r]);
                a2[r] = fmaf(w4.z, xv, a2[r]);
                a3[r] = fmaf(w4.w, xv, a3[r]);
            }
        }
        #pragma unroll
        for (int r = 0; r < 4; r++) {
            pb[0][r][dg][oq] = a0[r]; pb[1][r][dg][oq] = a1[r];
            pb[2][r][dg][oq] = a2[r]; pb[3][r][dg][oq] = a3[r];
        }
    }
    __syncthreads();
    {
        float s = 0.f;
        #pragma unroll
        for (int d16 = 0; d16 < 16; d16++) s += pb[o & 3][rr][d16][o >> 2];
        vs2[rr][o] = s + b_m2[o] * satt[rr];
    }
    __syncthreads();

    // GEMV2: v2 = relu(v1 @ W_o1^T + b_o1)
    {
        float a0[4], a1[4], a2[4], a3[4];
        #pragma unroll
        for (int r = 0; r < 4; r++) { a0[r]=0.f; a1[r]=0.f; a2[r]=0.f; a3[r]=0.f; }
        #pragma unroll
        for (int k = 0; k < 8; k++) {
            int d = dg * 8 + k;
            float4 w4 = *(const float4*)(Wt_o1 + d * DD + oq * 4);
            #pragma unroll
            for (int r = 0; r < 4; r++) {
                float xv = vs2[r][d];
                a0[r] = fmaf(w4.x, xv, a0[r]);
                a1[r] = fmaf(w4.y, xv, a1[r]);
                a2[r] = fmaf(w4.z, xv, a2[r]);
                a3[r] = fmaf(w4.w, xv, a3[r]);
            }
        }
        #pragma unroll
        for (int r = 0; r < 4; r++) {
            pb[0][r][dg][oq] = a0[r]; pb[1][r][dg][oq] = a1[r];
            pb[2][r][dg][oq] = a2[r]; pb[3][r][dg][oq] = a3[r];
        }
    }
    __syncthreads();
    {
        float s = 0.f;
        #pragma unroll
        for (int d16 = 0; d16 < 16; d16++) s += pb[o & 3][rr][d16][o >> 2];
        vs[rr][o] = fmaxf(s + b_o1[o], 0.f);
    }
    __syncthreads();

    // GEMV3: v3 = v2 @ W_o2^T + b_o2
    {
        float a0[4], a1[4], a2[4], a3[4];
        #pragma unroll
        for (int r = 0; r < 4; r++) { a0[r]=0.f; a1[r]=0.f; a2[r]=0.f; a3[r]=0.f; }
        #pragma unroll
        for (int k = 0; k < 8; k++) {
            int d = dg * 8 + k;
            float4 w4 = *(const float4*)(Wt_o2 + d * DD + oq * 4);
            #pragma unroll
            for (int r = 0; r < 4; r++) {
                float xv = vs[r][d];
                a0[r] = fmaf(w4.x, xv, a0[r]);
                a1[r] = fmaf(w4.y, xv, a1[r]);
                a2[r] = fmaf(w4.z, xv, a2[r]);
                a3[r] = fmaf(w4.w, xv, a3[r]);
            }
        }
        #pragma unroll
        for (int r = 0; r < 4; r++) {
            pb[0][r][dg][oq] = a0[r]; pb[1][r][dg][oq] = a1[r];
            pb[2][r][dg][oq] = a2[r]; pb[3][r][dg][oq] = a3[r];
        }
    }
    __syncthreads();

    float v;
    {
        float s = 0.f;
        #pragma unroll
        for (int d16 = 0; d16 < 16; d16++) s += pb[o & 3][rr][d16][o >> 2];
        v = s + b_o2[o] + h[(r0 + rr) * DD + o];   // + residual
    }

    // layernorm over d (128 threads = 2 waves per row)
    {
        float p1 = v, p2 = v * v;
        #pragma unroll
        for (int off = 32; off >= 1; off >>= 1) {
            p1 += __shfl_down(p1, off, 64);
            p2 += __shfl_down(p2, off, 64);
        }
        int wid = (t >> 6) & 1;
        if ((t & 63) == 0) { redsc[wid][0][rr] = p1; redsc[wid][1][rr] = p2; }
    }
    __syncthreads();
    {
        float sum = redsc[0][0][rr] + redsc[1][0][rr];
        float sq  = redsc[0][1][rr] + redsc[1][1][rr];
        float mu  = sum * (1.0f / DD);
        float var = sq * (1.0f / DD) - mu * mu;
        float inv = rsqrtf(var + 1e-5f);
        out[(r0 + rr) * DD + o] = fmaxf(fmaf((v - mu) * inv, ln_g[o], ln_b[o]), 0.f);
    }
}

extern "C" void kernel_launch(void* const* d_in, const int* in_sizes, int n_in,
                              void* d_out, int out_size, void* d_ws, size_t ws_size,
                              hipStream_t stream)
{
    (void)in_sizes; (void)n_in; (void)out_size; (void)ws_size;
    const float* x     = (const float*)d_in[0];
    const float* adj   = (const float*)d_in[1];
    const float* W_lin = (const float*)d_in[2];
    const float* b_lin = (const float*)d_in[3];
    const float* W_m1  = (const float*)d_in[4];
    const float* b_m1  = (const float*)d_in[5];
    const float* W_m2  = (const float*)d_in[6];
    const float* b_m2  = (const float*)d_in[7];
    const float* W_att = (const float*)d_in[8];
    const float* b_att = (const float*)d_in[9];
    const float* W_o1  = (const float*)d_in[10];
    const float* b_o1  = (const float*)d_in[11];
    const float* W_o2  = (const float*)d_in[12];
    const float* b_o2  = (const float*)d_in[13];
    const float* ln_g  = (const float*)d_in[14];
    const float* ln_b  = (const float*)d_in[15];

    float* out     = (float*)d_out;
    float* out_adj = out + ROWS * DD;

    float* ws    = (float*)d_ws;
    float* hm1   = ws;                    // 131072
    float* dotL  = ws + 131072;           // 1024
    float* dotR  = ws + 132096;           // 1024
    float* h     = ws + 133120;           // 131072
    float* Wt_m2 = ws + 264192;           // 16384
    float* Wt_o1 = ws + 280576;           // 16384
    float* Wt_o2 = ws + 296960;           // 16384

    hipLaunchKernelGGL(k_rows, dim3(ROWS / NR), dim3(128), 0, stream,
                       x, W_lin, b_lin, W_m1, b_m1, W_att, W_m2, W_o1, W_o2,
                       h, hm1, dotL, dotR, Wt_m2, Wt_o1, Wt_o2);
    hipLaunchKernelGGL(k_msgout, dim3(ROWS / NR), dim3(512), 0, stream,
                       adj, hm1, dotL, dotR, W_m1, W_att, b_att,
                       Wt_m2, b_m2, Wt_o1, b_o1, Wt_o2, b_o2,
                       h, ln_g, ln_b, out, out_adj);
}